// Round 12
// baseline (1444.778 us; speedup 1.0000x reference)
//
#include <hip/hip_runtime.h>

// ---------------------------------------------------------------------------
// GinkaBottleneck: transformer(4 layers, T=16, D=512) + GCN + fusion, B=2048.
// R11: GEMM core frozen (R10 8-phase, equals R6). New gemm64ln kernel fuses
// bias(+residual)+row-LayerNorm(+pos) into the N=512 GEMMs (emb, WO, FF2):
// BM=64 BN=512 BK=32, 8 waves 1Mx8N, 72 KiB LDS -> 2 blocks/CU, cross-wave
// LN reduction through 4 KB LDS. Removes 9 ln_kernel dispatches + FF2's
// intermediate buffer round-trip (~110+ us of traffic/dispatch overhead).
// ---------------------------------------------------------------------------

typedef _Float16 f16;
typedef f16 f16x8 __attribute__((ext_vector_type(8)));
typedef f16 f16x4 __attribute__((ext_vector_type(4)));
typedef float f32x4 __attribute__((ext_vector_type(4)));

__device__ inline float wred_sum(float s) {
#pragma unroll
  for (int m = 32; m; m >>= 1) s += __shfl_xor(s, m);
  return s;
}

// ---------------- weight convert: f32 [K,N] -> f16 [N,K] (or copy) ----------
struct WDesc {
  const float* src;
  f16* dst;
  int K, N, tiles_n, tile_base, mode;  // mode 0 = transpose, 1 = copy
};
struct WTable {
  WDesc d[32];
  int n;
};

__global__ void wconvert_kernel(WTable tab) {
  const int tile = blockIdx.x;
  int di = 0;
  while (di + 1 < tab.n && tab.d[di + 1].tile_base <= tile) ++di;
  const WDesc w = tab.d[di];
  const int t = tile - w.tile_base;
  const int tk = t / w.tiles_n, tn = t % w.tiles_n;
  const int tid = threadIdx.x;
  const int rr = tid >> 5, cc = tid & 31;
  __shared__ float tb[32][33];
  if (w.mode == 0) {
#pragma unroll
    for (int i = 0; i < 4; i++) {
      const int k = tk * 32 + i * 8 + rr, n = tn * 32 + cc;
      tb[i * 8 + rr][cc] = w.src[(size_t)k * w.N + n];
    }
    __syncthreads();
#pragma unroll
    for (int i = 0; i < 4; i++) {
      const int n = tn * 32 + i * 8 + rr, k = tk * 32 + cc;
      w.dst[(size_t)n * w.K + k] = (f16)tb[cc][i * 8 + rr];
    }
  } else {
#pragma unroll
    for (int i = 0; i < 4; i++) {
      const int k = tk * 32 + i * 8 + rr, n = tn * 32 + cc;
      w.dst[(size_t)k * w.N + n] = (f16)w.src[(size_t)k * w.N + n];
    }
  }
}

__global__ void biaspack_kernel(const float* __restrict__ bq,
                                const float* __restrict__ bk,
                                const float* __restrict__ bv,
                                float* __restrict__ bqkv) {
  const int i = blockIdx.x * 256 + threadIdx.x;
  if (i >= 4 * 1536) return;
  const int l = i / 1536, j = i % 1536;
  float v;
  if (j < 512)       v = bq[l * 512 + j];
  else if (j < 1024) v = bk[l * 512 + j - 512];
  else               v = bv[l * 512 + j - 1024];
  bqkv[i] = v;
}

// ---------------- prep: x[b,c,t] (f32) -> X0[b*16+t, c] (f16) ---------------
__global__ void prep_kernel(const float* __restrict__ x, f16* __restrict__ X0) {
  const int b = blockIdx.x;
  for (int c = threadIdx.x; c < 512; c += 256) {
    const float* src = x + ((size_t)b * 512 + c) * 16;
    float vals[16];
#pragma unroll
    for (int i = 0; i < 4; i++) {
      const float4 v = ((const float4*)src)[i];
      vals[i * 4 + 0] = v.x; vals[i * 4 + 1] = v.y;
      vals[i * 4 + 2] = v.z; vals[i * 4 + 3] = v.w;
    }
#pragma unroll
    for (int t = 0; t < 16; t++)
      X0[((size_t)b * 16 + t) * 512 + c] = (f16)vals[t];
  }
}

// ---------------- GEMM 256x256, 8-phase: C = A[M,K] * Bt[N,K]^T -------------
// (frozen R10 core) OUT: 0 = f16 (+bias, opt relu); 3 = InstanceNorm16+ELU
// NCHW f32 write.
#define STAGE_SLOT(TI, ISB, HALF)                                              \
  {                                                                            \
    f16* dstb_ = smw + ((TI) & 1) * 32768 + ((ISB) ? 16384 : 0) +              \
                 (HALF) * 8192 + ldsw2;                                        \
    const int ld_ = (ISB) ? ldb : lda;                                         \
    const f16* src_ = ((ISB) ? gBs : gAs) + (size_t)((HALF) * 128) * ld_ +     \
                      ((size_t)(TI) << 6);                                     \
    __builtin_amdgcn_global_load_lds(                                          \
        (const __attribute__((address_space(1))) void*)(src_),                 \
        (__attribute__((address_space(3))) void*)(dstb_), 16, 0, 0);           \
    __builtin_amdgcn_global_load_lds(                                          \
        (const __attribute__((address_space(1))) void*)(src_ + (size_t)64 * ld_), \
        (__attribute__((address_space(3))) void*)(dstb_ + 4096), 16, 0, 0);    \
  }

#define VM4 asm volatile("s_waitcnt vmcnt(4)" ::: "memory");
#define VM0 asm volatile("s_waitcnt vmcnt(0)" ::: "memory");
#define VMN

#define PHASE(TI, P, FIRST, DOSTG, STI, SISB, SHALF, VM)                       \
  {                                                                            \
    const f16* Ab_ = smw + ((TI) & 1) * 32768;                                 \
    const f16* Bb_ = Ab_ + 16384;                                              \
    if (FIRST) {                                                               \
      _Pragma("unroll") for (int n = 0; n < 4; ++n) {                          \
        const int r = wn + n * 16 + rm;                                        \
        bf[n][0] = *(const f16x8*)(Bb_ + r * 64 + koff0);                      \
        bf[n][1] = *(const f16x8*)(Bb_ + r * 64 + koff1);                      \
      }                                                                        \
    }                                                                          \
    const int r0_ = wm + (2 * (P)) * 16 + rm;                                  \
    const f16x8 a0k0 = *(const f16x8*)(Ab_ + r0_ * 64 + koff0);                \
    const f16x8 a0k1 = *(const f16x8*)(Ab_ + r0_ * 64 + koff1);                \
    const f16x8 a1k0 = *(const f16x8*)(Ab_ + (r0_ + 16) * 64 + koff0);         \
    const f16x8 a1k1 = *(const f16x8*)(Ab_ + (r0_ + 16) * 64 + koff1);         \
    if (DOSTG) STAGE_SLOT(STI, SISB, SHALF)                                    \
    VM                                                                         \
    __builtin_amdgcn_s_barrier();                                              \
    asm volatile("s_waitcnt lgkmcnt(0)" ::: "memory");                         \
    __builtin_amdgcn_sched_barrier(0);                                         \
    __builtin_amdgcn_s_setprio(1);                                             \
    _Pragma("unroll") for (int n = 0; n < 4; ++n) {                            \
      acc[2 * (P)][n] = __builtin_amdgcn_mfma_f32_16x16x32_f16(                \
          a0k0, bf[n][0], acc[2 * (P)][n], 0, 0, 0);                           \
      acc[2 * (P)][n] = __builtin_amdgcn_mfma_f32_16x16x32_f16(                \
          a0k1, bf[n][1], acc[2 * (P)][n], 0, 0, 0);                           \
      acc[2 * (P) + 1][n] = __builtin_amdgcn_mfma_f32_16x16x32_f16(            \
          a1k0, bf[n][0], acc[2 * (P) + 1][n], 0, 0, 0);                       \
      acc[2 * (P) + 1][n] = __builtin_amdgcn_mfma_f32_16x16x32_f16(            \
          a1k1, bf[n][1], acc[2 * (P) + 1][n], 0, 0, 0);                       \
    }                                                                          \
    __builtin_amdgcn_s_setprio(0);                                             \
    __builtin_amdgcn_s_barrier();                                              \
    __builtin_amdgcn_sched_barrier(0);                                         \
  }

template <int OUT, bool RELU, bool HASB, int NT>
__global__ __launch_bounds__(512) void gemm256_kernel(
    const f16* __restrict__ A, const f16* __restrict__ Bt, void* __restrict__ C,
    const float* __restrict__ bias, const f16* __restrict__ resp,
    int N, int lda, int ldb) {
  __shared__ alignas(16) f16 smem[65536];  // 128 KiB
  f16* smw = smem;
  const int tid = threadIdx.x;
  const int nb = N >> 8;
  const int cpx = gridDim.x >> 3;  // grid always a multiple of 8
  const int wg = (blockIdx.x & 7) * cpx + (blockIdx.x >> 3);
  const int bx = wg % nb, by = wg / nb;
  const int row0 = by << 8, col0 = bx << 8;
  const int lane = tid & 63;
  const int wid = tid >> 6;
  const int wm = (wid >> 2) << 7;  // 0 / 128
  const int wn = (wid & 3) << 6;   // 0 / 64 / 128 / 192
  const int rm = lane & 15;
  const int kg = lane >> 4;
  const int key = rm & 7;
  const int koff0 = ((kg ^ key)) << 3;
  const int koff1 = (((4 + kg) ^ key)) << 3;
  const int schunk = (tid & 7) ^ ((tid >> 3) & 7);
  const f16* gAs = A + (size_t)(row0 + (tid >> 3)) * lda + (schunk << 3);
  const f16* gBs = Bt + (size_t)(col0 + (tid >> 3)) * ldb + (schunk << 3);
  const int ldsw2 = (tid & 0x1C0) << 3;  // wave*512 elems
  f32x4 acc[8][4] = {};
  f16x8 bf[4][2];

  STAGE_SLOT(0, 0, 0)
  STAGE_SLOT(0, 0, 1)
  STAGE_SLOT(0, 1, 0)
  STAGE_SLOT(0, 1, 1)
  STAGE_SLOT(1, 1, 0)
  STAGE_SLOT(1, 1, 1)
  VM4
  __builtin_amdgcn_s_barrier();
  __builtin_amdgcn_sched_barrier(0);

#pragma unroll 1
  for (int j = 0; j < NT / 2 - 1; ++j) {
    const int u = 2 * j, v = u + 1, t2 = u + 2, t3 = u + 3;
    PHASE(u, 0, true,  true, v,  0, 0, VMN)
    PHASE(u, 1, false, true, v,  0, 1, VMN)
    PHASE(u, 2, false, true, t2, 1, 0, VMN)
    PHASE(u, 3, false, true, t2, 1, 1, VM4)
    PHASE(v, 0, true,  true, t2, 0, 0, VMN)
    PHASE(v, 1, false, true, t2, 0, 1, VMN)
    PHASE(v, 2, false, true, t3, 1, 0, VMN)
    PHASE(v, 3, false, true, t3, 1, 1, VM4)
  }
  {  // peeled last iter
    const int u = NT - 2, v = NT - 1;
    PHASE(u, 0, true,  true,  v, 0, 0, VMN)
    PHASE(u, 1, false, true,  v, 0, 1, VMN)
    PHASE(u, 2, false, false, 0, 0, 0, VMN)
    PHASE(u, 3, false, false, 0, 0, 0, VM0)
    PHASE(v, 0, true,  false, 0, 0, 0, VMN)
    PHASE(v, 1, false, false, 0, 0, 0, VMN)
    PHASE(v, 2, false, false, 0, 0, 0, VMN)
    PHASE(v, 3, false, false, 0, 0, 0, VMN)
  }

  const int cn = lane & 15;
  const int rg = (lane >> 4) << 2;
  if (OUT == 3) {
    float* out = (float*)C;
#pragma unroll
    for (int m = 0; m < 8; ++m) {
      const int bidx = (row0 >> 4) + (wm >> 4) + m;
#pragma unroll
      for (int n = 0; n < 4; ++n) {
        const int col = col0 + wn + n * 16 + cn;
        const float v0 = acc[m][n][0], v1 = acc[m][n][1];
        const float v2 = acc[m][n][2], v3 = acc[m][n][3];
        float s = v0 + v1 + v2 + v3;
        s += __shfl_xor(s, 16);
        s += __shfl_xor(s, 32);
        const float mu = s * (1.f / 16.f);
        float q = (v0 - mu) * (v0 - mu) + (v1 - mu) * (v1 - mu) +
                  (v2 - mu) * (v2 - mu) + (v3 - mu) * (v3 - mu);
        q += __shfl_xor(q, 16);
        q += __shfl_xor(q, 32);
        const float rstd = rsqrtf(q * (1.f / 16.f) + 1e-5f);
        float4 z;
        z.x = (v0 - mu) * rstd; z.x = z.x > 0.f ? z.x : expm1f(z.x);
        z.y = (v1 - mu) * rstd; z.y = z.y > 0.f ? z.y : expm1f(z.y);
        z.z = (v2 - mu) * rstd; z.z = z.z > 0.f ? z.z : expm1f(z.z);
        z.w = (v3 - mu) * rstd; z.w = z.w > 0.f ? z.w : expm1f(z.w);
        *(float4*)(out + ((size_t)bidx * 512 + col) * 16 + rg) = z;
      }
    }
  } else {
#pragma unroll
    for (int m = 0; m < 8; ++m) {
#pragma unroll
      for (int n = 0; n < 4; ++n) {
        const int col = col0 + wn + n * 16 + cn;
        const float bv = HASB ? bias[col] : 0.0f;
#pragma unroll
        for (int r = 0; r < 4; ++r) {
          const int row = row0 + wm + m * 16 + rg + r;
          float v = acc[m][n][r] + bv;
          if (OUT == 4) v += (float)resp[(size_t)row * N + col];
          if (RELU) v = v > 0.f ? v : 0.f;
          ((f16*)C)[(size_t)row * N + col] = (f16)v;
        }
      }
    }
  }
}

// ---------------- GEMM 64x512 + fused bias(+res)+row-LN(+pos) ---------------
// BM=64, BN=512, BK=32, 8 waves 1Mx8N (wave C 64x64, acc[4][4]). 2 LDS bufs
// of {A[64][32] | B[512][32]} = 36 KB each (72 KB total -> 2 blocks/CU).
// Drain-to-0 per K-step; the co-resident block covers the stall.
// Epilogue: v = acc + bias (+res); 16-lane shfl partial sums; cross-wave
// combine via 4 KB LDS; out = (v-mu)*rstd*g + b (+pos). NT must be such that
// grid = M/64 = 512 (multiple of 8). LNMODE: 1 = +res, 2 = +pos after LN.
template <int LNMODE, int NT>
__global__ __launch_bounds__(512) void gemm64ln_kernel(
    const f16* __restrict__ A, const f16* __restrict__ Bt, f16* __restrict__ outp,
    const float* __restrict__ bias, const f16* resp,
    const float* __restrict__ g, const float* __restrict__ bvec,
    const float* __restrict__ pos, int lda) {
  constexpr int K = NT * 32;
  __shared__ alignas(16) f16 smem[2][18432];  // per buf: A 2048 f16 | B 16384 f16
  const int tid = threadIdx.x;
  const int cpx = gridDim.x >> 3;
  const int wg = (blockIdx.x & 7) * cpx + (blockIdx.x >> 3);
  const int row0 = wg << 6;
  const int lane = tid & 63;
  const int wid = tid >> 6;
  const int wn = wid << 6;
  const int rm = lane & 15;
  const int kg = lane >> 4;
  const int koff = (kg ^ ((rm >> 1) & 3)) << 3;
  const int srow = tid >> 2;
  const int schunk = (tid & 3) ^ ((tid >> 3) & 3);
  const f16* gAs = A + (size_t)(row0 + srow) * lda + (schunk << 3);
  const f16* gBs = Bt + (size_t)srow * K + (schunk << 3);
  const int ldsw = (tid & 0x1C0) << 3;
  f32x4 acc[4][4] = {};

  auto STAGE = [&](int t) {
    f16* buf = smem[t & 1];
    const int kt = t << 5;
    if (tid < 256)
      __builtin_amdgcn_global_load_lds(
          (const __attribute__((address_space(1))) void*)(gAs + kt),
          (__attribute__((address_space(3))) void*)(buf + ldsw), 16, 0, 0);
#pragma unroll
    for (int i = 0; i < 4; ++i)
      __builtin_amdgcn_global_load_lds(
          (const __attribute__((address_space(1))) void*)(gBs + (size_t)(i * 128) * K + kt),
          (__attribute__((address_space(3))) void*)(buf + 2048 + i * 4096 + ldsw),
          16, 0, 0);
  };

  STAGE(0);
  asm volatile("s_waitcnt vmcnt(0)" ::: "memory");
  __builtin_amdgcn_s_barrier();
  __builtin_amdgcn_sched_barrier(0);

#pragma unroll 1
  for (int t = 0; t < NT; ++t) {
    if (t + 1 < NT) STAGE(t + 1);
    const f16* buf = smem[t & 1];
    f16x8 af[4], bf[4];
#pragma unroll
    for (int n = 0; n < 4; ++n)
      bf[n] = *(const f16x8*)(buf + 2048 + ((wn + n * 16 + rm) << 5) + koff);
#pragma unroll
    for (int m = 0; m < 4; ++m)
      af[m] = *(const f16x8*)(buf + ((m * 16 + rm) << 5) + koff);
    __builtin_amdgcn_s_setprio(1);
#pragma unroll
    for (int m = 0; m < 4; ++m)
#pragma unroll
      for (int n = 0; n < 4; ++n)
        acc[m][n] =
            __builtin_amdgcn_mfma_f32_16x16x32_f16(af[m], bf[n], acc[m][n], 0, 0, 0);
    __builtin_amdgcn_s_setprio(0);
    if (t + 1 < NT) {
      asm volatile("s_waitcnt vmcnt(0)" ::: "memory");
      __builtin_amdgcn_s_barrier();
      __builtin_amdgcn_sched_barrier(0);
    }
  }

  // ---- epilogue: bias (+res), row stats, normalize, write ----
  const int cn = lane & 15;
  const int rg = (lane >> 4) << 2;
  float biasn[4];
#pragma unroll
  for (int n = 0; n < 4; ++n) biasn[n] = bias[wn + n * 16 + cn];
#pragma unroll
  for (int m = 0; m < 4; ++m)
#pragma unroll
    for (int n = 0; n < 4; ++n) {
      const int col = wn + n * 16 + cn;
#pragma unroll
      for (int r = 0; r < 4; ++r) {
        float val = acc[m][n][r] + biasn[n];
        if (LNMODE == 1)
          val += (float)resp[(size_t)(row0 + m * 16 + rg + r) * 512 + col];
        acc[m][n][r] = val;
      }
    }
  float* part = (float*)smem;  // [64 rows][8 waves][2] = 4 KB
  __syncthreads();             // all LDS reads of the K-loop are done
#pragma unroll
  for (int m = 0; m < 4; ++m)
#pragma unroll
    for (int r = 0; r < 4; ++r) {
      float s = 0, q = 0;
#pragma unroll
      for (int n = 0; n < 4; ++n) {
        const float val = acc[m][n][r];
        s += val;
        q += val * val;
      }
      s += __shfl_xor(s, 1); s += __shfl_xor(s, 2);
      s += __shfl_xor(s, 4); s += __shfl_xor(s, 8);
      q += __shfl_xor(q, 1); q += __shfl_xor(q, 2);
      q += __shfl_xor(q, 4); q += __shfl_xor(q, 8);
      if (cn == 0) {
        part[(m * 16 + rg + r) * 16 + wid * 2] = s;
        part[(m * 16 + rg + r) * 16 + wid * 2 + 1] = q;
      }
    }
  __syncthreads();
  float mu_[4][4], rs_[4][4];
#pragma unroll
  for (int m = 0; m < 4; ++m)
#pragma unroll
    for (int r = 0; r < 4; ++r) {
      const int row = m * 16 + rg + r;
      float S = 0, Q = 0;
#pragma unroll
      for (int w = 0; w < 8; ++w) {
        S += part[row * 16 + w * 2];
        Q += part[row * 16 + w * 2 + 1];
      }
      const float mu = S * (1.f / 512.f);
      mu_[m][r] = mu;
      rs_[m][r] = rsqrtf(Q * (1.f / 512.f) - mu * mu + 1e-5f);
    }
  float gv[4], bv2[4];
#pragma unroll
  for (int n = 0; n < 4; ++n) {
    gv[n] = g[wn + n * 16 + cn];
    bv2[n] = bvec[wn + n * 16 + cn];
  }
#pragma unroll
  for (int m = 0; m < 4; ++m)
#pragma unroll
    for (int n = 0; n < 4; ++n) {
      const int col = wn + n * 16 + cn;
#pragma unroll
      for (int r = 0; r < 4; ++r) {
        float o = (acc[m][n][r] - mu_[m][r]) * rs_[m][r] * gv[n] + bv2[n];
        if (LNMODE == 2) o += pos[(rg + r) * 512 + col];  // t = local row & 15
        outp[(size_t)(row0 + m * 16 + rg + r) * 512 + col] = (f16)o;
      }
    }
}

// ---------------- lnpack: F[:, :512] = LN(fc_out); F[:, 512:] = X2 ----------
__global__ void lnpack_kernel(const f16* __restrict__ in, const f16* __restrict__ x2,
                              const float* __restrict__ g, const float* __restrict__ b,
                              f16* __restrict__ F) {
  const int row = (blockIdx.x << 2) + (threadIdx.x >> 6);
  const int lane = threadIdx.x & 63;
  const int c0 = lane << 3;
  const f16x8 xi = *(const f16x8*)(in + (size_t)row * 512 + c0);
  float v[8];
#pragma unroll
  for (int j = 0; j < 8; j++) v[j] = (float)xi[j];
  float s = 0;
#pragma unroll
  for (int j = 0; j < 8; j++) s += v[j];
  s = wred_sum(s);
  const float mu = s * (1.f / 512.f);
  float q = 0;
#pragma unroll
  for (int j = 0; j < 8; j++) {
    const float d = v[j] - mu;
    q += d * d;
  }
  q = wred_sum(q);
  const float rstd = rsqrtf(q * (1.f / 512.f) + 1e-5f);
  f16x8 o8;
#pragma unroll
  for (int j = 0; j < 8; j++)
    o8[j] = (f16)((v[j] - mu) * rstd * g[c0 + j] + b[c0 + j]);
  *(f16x8*)(F + (size_t)row * 1024 + c0) = o8;
  const f16x8 x2v = *(const f16x8*)(x2 + (size_t)row * 512 + c0);
  *(f16x8*)(F + (size_t)row * 1024 + 512 + c0) = x2v;
}

// ---------------- attention: MFMA, one (b,head) per wave, 4 waves/block -----
__global__ __launch_bounds__(256) void attn_kernel(const f16* __restrict__ qkv,
                                                   f16* __restrict__ o) {
  __shared__ f16 smem[4][3776];  // per wave: Q[16][72] K[16][72] V[16][72] P[16][20]
  const int wid = threadIdx.x >> 6;
  const int lane = threadIdx.x & 63;
  const int bh = (blockIdx.x << 2) + wid;
  const int b = bh >> 3, h = bh & 7;
  f16* W = smem[wid];
  f16* Qw = W;
  f16* Kw = W + 1152;
  f16* Vw = W + 2304;
  f16* Pw = W + 3456;
  const size_t base = (size_t)b * 24576 + (size_t)h * 64;
#pragma unroll
  for (int i = 0; i < 6; i++) {
    const int c = i * 64 + lane;
    const int t = c / 24;
    const int rem = c - t * 24;
    const int mat = rem >> 3, ch = rem & 7;
    const f16x8 v = *(const f16x8*)(qkv + base + (size_t)t * 1536 + mat * 512 + ch * 8);
    *(f16x8*)(W + mat * 1152 + t * 72 + ch * 8) = v;
  }
  __syncthreads();
  const int rm = lane & 15, kg = lane >> 4;
  f32x4 s4 = {};
  {
    const f16x8 q0 = *(const f16x8*)(Qw + rm * 72 + kg * 8);
    const f16x8 q1 = *(const f16x8*)(Qw + rm * 72 + 32 + kg * 8);
    const f16x8 k0 = *(const f16x8*)(Kw + rm * 72 + kg * 8);
    const f16x8 k1 = *(const f16x8*)(Kw + rm * 72 + 32 + kg * 8);
    s4 = __builtin_amdgcn_mfma_f32_16x16x32_f16(q0, k0, s4, 0, 0, 0);
    s4 = __builtin_amdgcn_mfma_f32_16x16x32_f16(q1, k1, s4, 0, 0, 0);
  }
  float p[4];
#pragma unroll
  for (int r = 0; r < 4; r++) {
    const float sv = s4[r] * 0.125f;
    float m = sv;
    m = fmaxf(m, __shfl_xor(m, 1));
    m = fmaxf(m, __shfl_xor(m, 2));
    m = fmaxf(m, __shfl_xor(m, 4));
    m = fmaxf(m, __shfl_xor(m, 8));
    const float e = expf(sv - m);
    float s = e;
    s += __shfl_xor(s, 1);
    s += __shfl_xor(s, 2);
    s += __shfl_xor(s, 4);
    s += __shfl_xor(s, 8);
    p[r] = e / s;
  }
#pragma unroll
  for (int r = 0; r < 4; r++) Pw[(kg * 4 + r) * 20 + rm] = (f16)p[r];
  __syncthreads();
  const f16x4 pa = *(const f16x4*)(Pw + rm * 20 + kg * 4);
  f32x4 o4[4] = {};
#pragma unroll
  for (int dt = 0; dt < 4; dt++) {
    f16x4 vb;
#pragma unroll
    for (int kk = 0; kk < 4; kk++) vb[kk] = Vw[(kg * 4 + kk) * 72 + dt * 16 + rm];
    o4[dt] = __builtin_amdgcn_mfma_f32_16x16x16f16(pa, vb, o4[dt], 0, 0, 0);
  }
  f16* op = o + (size_t)b * 16 * 512 + (size_t)h * 64;
#pragma unroll
  for (int dt = 0; dt < 4; dt++)
#pragma unroll
    for (int r = 0; r < 4; r++)
      op[(size_t)(kg * 4 + r) * 512 + dt * 16 + rm] = (f16)o4[dt][r];
}

// ---------------- GCN adj-mix + bias + LN + ELU (one block per b) -----------
template <int DG>
__global__ __launch_bounds__(256) void adjmix_kernel(
    const f16* __restrict__ r, const float* __restrict__ adj,
    const float* __restrict__ bias, const float* __restrict__ g,
    const float* __restrict__ bet, f16* __restrict__ out, int ldo) {
  const int b = blockIdx.x;
  const int tid = threadIdx.x;
  __shared__ float agg[16][DG];
  __shared__ float adjs[256];
  if (tid < 256) adjs[tid] = adj[tid];
  __syncthreads();
  const int d0 = tid * 4;
  if (d0 < DG) {
    float acc[16][4];
#pragma unroll
    for (int m = 0; m < 16; m++)
#pragma unroll
      for (int j = 0; j < 4; j++) acc[m][j] = 0.f;
#pragma unroll
    for (int n = 0; n < 16; n++) {
      const f16x4 v = *(const f16x4*)(r + ((size_t)b * 16 + n) * DG + d0);
      const float v0 = (float)v[0], v1 = (float)v[1], v2 = (float)v[2], v3 = (float)v[3];
#pragma unroll
      for (int m = 0; m < 16; m++) {
        const float a = adjs[m * 16 + n];
        acc[m][0] += a * v0;
        acc[m][1] += a * v1;
        acc[m][2] += a * v2;
        acc[m][3] += a * v3;
      }
    }
    const float4 bv = *(const float4*)(bias + d0);
#pragma unroll
    for (int m = 0; m < 16; m++) {
      agg[m][d0 + 0] = acc[m][0] + bv.x;
      agg[m][d0 + 1] = acc[m][1] + bv.y;
      agg[m][d0 + 2] = acc[m][2] + bv.z;
      agg[m][d0 + 3] = acc[m][3] + bv.w;
    }
  }
  __syncthreads();
  const int wave = tid >> 6, lane = tid & 63;
  for (int m = wave; m < 16; m += 4) {
    float s = 0;
#pragma unroll
    for (int j = 0; j < DG / 64; j++) s += agg[m][j * 64 + lane];
    s = wred_sum(s);
    const float mu = s / DG;
    float q = 0;
#pragma unroll
    for (int j = 0; j < DG / 64; j++) {
      const float t = agg[m][j * 64 + lane] - mu;
      q += t * t;
    }
    q = wred_sum(q);
    const float rstd = rsqrtf(q / DG + 1e-5f);
    const size_t grow = (size_t)b * 16 + m;
#pragma unroll
    for (int j = 0; j < DG / 64; j++) {
      const int d = j * 64 + lane;
      float v = (agg[m][d] - mu) * rstd * g[d] + bet[d];
      v = v > 0.f ? v : expm1f(v);
      out[grow * ldo + d] = (f16)v;
    }
  }
}

// ---------------------------------------------------------------------------
extern "C" void kernel_launch(void* const* d_in, const int* in_sizes, int n_in,
                              void* d_out, int out_size, void* d_ws, size_t ws_size,
                              hipStream_t stream) {
  (void)in_sizes; (void)n_in; (void)out_size; (void)ws_size;
  const float* x         = (const float*)d_in[0];
  const float* emb_w     = (const float*)d_in[1];
  const float* emb_b     = (const float*)d_in[2];
  const float* emb_ln_g  = (const float*)d_in[3];
  const float* emb_ln_b  = (const float*)d_in[4];
  const float* pos       = (const float*)d_in[5];
  const float* attn_wq   = (const float*)d_in[6];
  const float* attn_wk   = (const float*)d_in[7];
  const float* attn_wv   = (const float*)d_in[8];
  const float* attn_bq   = (const float*)d_in[9];
  const float* attn_bk   = (const float*)d_in[10];
  const float* attn_bv   = (const float*)d_in[11];
  const float* attn_wo   = (const float*)d_in[12];
  const float* attn_bo   = (const float*)d_in[13];
  const float* ln1_g     = (const float*)d_in[14];
  const float* ln1_b     = (const float*)d_in[15];
  const float* ff_w1     = (const float*)d_in[16];
  const float* ff_b1     = (const float*)d_in[17];
  const float* ff_w2     = (const float*)d_in[18];
  const float* ff_b2     = (const float*)d_in[19];
  const float* ln2_g     = (const float*)d_in[20];
  const float* ln2_b     = (const float*)d_in[21];
  const float* fc_w      = (const float*)d_in[22];
  const float* fc_b      = (const float*)d_in[23];
  const float* fc_ln_g   = (const float*)d_in[24];
  const float* fc_ln_b   = (const float*)d_in[25];
  const float* gcn_w1    = (const float*)d_in[26];
  const float* gcn_b1    = (const float*)d_in[27];
  const float* gcn_ln1_g = (const float*)d_in[28];
  const float* gcn_ln1_b = (const float*)d_in[29];
  const float* gcn_w2    = (const float*)d_in[30];
  const float* gcn_b2    = (const float*)d_in[31];
  const float* gcn_ln2_g = (const float*)d_in[32];
  const float* gcn_ln2_b = (const float*)d_in[33];
  const float* fusion_w  = (const float*)d_in[34];
  const float* fusion_b  = (const float*)d_in[35];
  const float* adj       = (const float*)d_in[36];
  (void)fusion_b;  // cancels under instance norm

  // ---- workspace map (bytes); peak ~212 MiB ----
  char* ws = (char*)d_ws;
  f16*   WF   = (f16*)(ws);                      // 20,971,520 B of weights
  float* BQKV = (float*)(ws + 20971520ull);      //     24,576 B
  f16*   Ap   = (f16*)(ws + 20996096ull);        // 32 MiB  (X0, then X2)
  f16*   Bp   = (f16*)(ws + 54550528ull);        // 32 MiB  (h; B..C = 64 MiB F)
  f16*   Cp   = (f16*)(ws + 88104960ull);        // 32 MiB  (scratch)
  f16*   Qp   = (f16*)(ws + 121659392ull);       // 96 MiB  (qkv / ff scratch)

  // WF layout (f16 element offsets)
  const size_t o_emb = 0, o_qkv = 262144, o_wo = 3407872, o_ff1 = 4456448,
               o_ff2 = 6553600, o_fc = 8650752, o_g1 = 8912896, o_g2 = 9437184,
               o_fus = 9961472;

  WTable tab{};
  int ntab = 0, tbase = 0;
  auto add = [&](const float* s, f16* dst, int K, int N, int mode) {
    WDesc& w = tab.d[ntab++];
    w.src = s; w.dst = dst; w.K = K; w.N = N;
    w.tiles_n = N / 32; w.tile_base = tbase; w.mode = mode;
    tbase += (K / 32) * (N / 32);
  };
  add(emb_w, WF + o_emb, 512, 512, 0);
  for (int l = 0; l < 4; l++) {
    add(attn_wq + l * 262144, WF + o_qkv + (size_t)l * 786432, 512, 512, 0);
    add(attn_wk + l * 262144, WF + o_qkv + (size_t)l * 786432 + 262144, 512, 512, 0);
    add(attn_wv + l * 262144, WF + o_qkv + (size_t)l * 786432 + 524288, 512, 512, 0);
  }
  for (int l = 0; l < 4; l++)
    add(attn_wo + l * 262144, WF + o_wo + (size_t)l * 262144, 512, 512, 0);
  for (int l = 0; l < 4; l++)
    add(ff_w1 + l * 524288, WF + o_ff1 + (size_t)l * 524288, 512, 1024, 0);
  for (int l = 0; l < 4; l++)
    add(ff_w2 + l * 524288, WF + o_ff2 + (size_t)l * 524288, 1024, 512, 0);
  add(fc_w, WF + o_fc, 512, 512, 0);
  add(gcn_w1, WF + o_g1, 512, 1024, 0);
  add(gcn_w2, WF + o_g2, 1024, 512, 0);
  add(fusion_w, WF + o_fus, 512, 1024, 1);  // already [N,K]: straight copy
  tab.n = ntab;

  wconvert_kernel<<<tbase, 256, 0, stream>>>(tab);
  biaspack_kernel<<<24, 256, 0, stream>>>(attn_bq, attn_bk, attn_bv, BQKV);
  prep_kernel<<<2048, 256, 0, stream>>>(x, Ap);  // X0 in A

  // ---- GCN branch ----
  gemm256_kernel<0, false, false, 8><<<512, 512, 0, stream>>>(
      Ap, WF + o_g1, Qp, nullptr, nullptr, 1024, 512, 512);
  adjmix_kernel<1024><<<2048, 256, 0, stream>>>(
      Qp, adj, gcn_b1, gcn_ln1_g, gcn_ln1_b, Bp, 1024);
  gemm256_kernel<0, false, false, 16><<<256, 512, 0, stream>>>(
      Bp, WF + o_g2, Qp, nullptr, nullptr, 512, 1024, 1024);

  // ---- transformer embed + LN + pos (fused) -> h in Bp ----
  gemm64ln_kernel<2, 16><<<512, 512, 0, stream>>>(
      Ap, WF + o_emb, Bp, emb_b, nullptr, emb_ln_g, emb_ln_b, pos, 512);

  // GCN adjmix2 -> X2 in A (A free now)
  adjmix_kernel<512><<<2048, 256, 0, stream>>>(
      Qp, adj, gcn_b2, gcn_ln2_g, gcn_ln2_b, Ap, 512);

  // ---- transformer layers (h=Bp, scratch=Cp, Qp free) ----
  for (int i = 0; i < 4; i++) {
    gemm256_kernel<0, false, true, 8><<<768, 512, 0, stream>>>(
        Bp, WF + o_qkv + (size_t)i * 786432, Qp, BQKV + i * 1536, nullptr,
        1536, 512, 512);
    attn_kernel<<<4096, 256, 0, stream>>>(Qp, Cp);
    // WO + bias + residual(h) + LN1 -> h (in place, per-element safe)
    gemm64ln_kernel<1, 16><<<512, 512, 0, stream>>>(
        Cp, WF + o_wo + (size_t)i * 262144, Bp, attn_bo + i * 512, Bp,
        ln1_g + i * 512, ln1_b + i * 512, nullptr, 512);
    gemm256_kernel<0, true, true, 8><<<512, 512, 0, stream>>>(
        Bp, WF + o_ff1 + (size_t)i * 524288, Qp, ff_b1 + i * 1024, nullptr,
        1024, 512, 512);
    // FF2 + bias + residual(h) + LN2 -> h (in place)
    gemm64ln_kernel<1, 32><<<512, 512, 0, stream>>>(
        Qp, WF + o_ff2 + (size_t)i * 524288, Bp, ff_b2 + i * 512, Bp,
        ln2_g + i * 512, ln2_b + i * 512, nullptr, 1024);
  }

  // ---- fc -> Qp; lnpack: F[:, :512]=LN(Qp), F[:, 512:]=X2 (F = Bp..Cp) ----
  gemm256_kernel<0, false, true, 8><<<256, 512, 0, stream>>>(
      Bp, WF + o_fc, Qp, fc_b, nullptr, 512, 512, 512);
  lnpack_kernel<<<8192, 256, 0, stream>>>(Qp, Ap, fc_ln_g, fc_ln_b, Bp);

  // ---- fusion GEMM K=1024 with fused InstanceNorm+ELU+NCHW epilogue ----
  gemm256_kernel<3, false, false, 16><<<256, 512, 0, stream>>>(
      Bp, WF + o_fus, d_out, nullptr, nullptr, 512, 1024, 1024);
}

// Round 13
// 1286.899 us; speedup vs baseline: 1.1227x; 1.1227x over previous
//
#include <hip/hip_runtime.h>

// ---------------------------------------------------------------------------
// GinkaBottleneck: transformer(4 layers, T=16, D=512) + GCN + fusion, B=2048.
// R12: revert to R10 (best measured: 1292 us). 8-phase gemm256 (BK=64, 2 dbuf
// x 2 half LDS, counted vmcnt(4) at ph4/8, both-sides row&7 swizzle, setprio)
// + residual-fused WO/FF2 epilogues (OUT=4) + standalone LN + fused
// InstanceNorm fusion-GEMM tail. R11's gemm64ln (small-tile LN fusion)
// regressed (93us/dispatch at 13% MfmaUtil) and is removed.
// ---------------------------------------------------------------------------

typedef _Float16 f16;
typedef f16 f16x8 __attribute__((ext_vector_type(8)));
typedef f16 f16x4 __attribute__((ext_vector_type(4)));
typedef float f32x4 __attribute__((ext_vector_type(4)));

__device__ inline float wred_sum(float s) {
#pragma unroll
  for (int m = 32; m; m >>= 1) s += __shfl_xor(s, m);
  return s;
}

// ---------------- weight convert: f32 [K,N] -> f16 [N,K] (or copy) ----------
struct WDesc {
  const float* src;
  f16* dst;
  int K, N, tiles_n, tile_base, mode;  // mode 0 = transpose, 1 = copy
};
struct WTable {
  WDesc d[32];
  int n;
};

__global__ void wconvert_kernel(WTable tab) {
  const int tile = blockIdx.x;
  int di = 0;
  while (di + 1 < tab.n && tab.d[di + 1].tile_base <= tile) ++di;
  const WDesc w = tab.d[di];
  const int t = tile - w.tile_base;
  const int tk = t / w.tiles_n, tn = t % w.tiles_n;
  const int tid = threadIdx.x;
  const int rr = tid >> 5, cc = tid & 31;
  __shared__ float tb[32][33];
  if (w.mode == 0) {
#pragma unroll
    for (int i = 0; i < 4; i++) {
      const int k = tk * 32 + i * 8 + rr, n = tn * 32 + cc;
      tb[i * 8 + rr][cc] = w.src[(size_t)k * w.N + n];
    }
    __syncthreads();
#pragma unroll
    for (int i = 0; i < 4; i++) {
      const int n = tn * 32 + i * 8 + rr, k = tk * 32 + cc;
      w.dst[(size_t)n * w.K + k] = (f16)tb[cc][i * 8 + rr];
    }
  } else {
#pragma unroll
    for (int i = 0; i < 4; i++) {
      const int k = tk * 32 + i * 8 + rr, n = tn * 32 + cc;
      w.dst[(size_t)k * w.N + n] = (f16)w.src[(size_t)k * w.N + n];
    }
  }
}

__global__ void biaspack_kernel(const float* __restrict__ bq,
                                const float* __restrict__ bk,
                                const float* __restrict__ bv,
                                float* __restrict__ bqkv) {
  const int i = blockIdx.x * 256 + threadIdx.x;
  if (i >= 4 * 1536) return;
  const int l = i / 1536, j = i % 1536;
  float v;
  if (j < 512)       v = bq[l * 512 + j];
  else if (j < 1024) v = bk[l * 512 + j - 512];
  else               v = bv[l * 512 + j - 1024];
  bqkv[i] = v;
}

// ---------------- prep: x[b,c,t] (f32) -> X0[b*16+t, c] (f16) ---------------
__global__ void prep_kernel(const float* __restrict__ x, f16* __restrict__ X0) {
  const int b = blockIdx.x;
  for (int c = threadIdx.x; c < 512; c += 256) {
    const float* src = x + ((size_t)b * 512 + c) * 16;
    float vals[16];
#pragma unroll
    for (int i = 0; i < 4; i++) {
      const float4 v = ((const float4*)src)[i];
      vals[i * 4 + 0] = v.x; vals[i * 4 + 1] = v.y;
      vals[i * 4 + 2] = v.z; vals[i * 4 + 3] = v.w;
    }
#pragma unroll
    for (int t = 0; t < 16; t++)
      X0[((size_t)b * 16 + t) * 512 + c] = (f16)vals[t];
  }
}

// ---------------- GEMM 256x256, 8-phase: C = A[M,K] * Bt[N,K]^T -------------
// 8 waves (2Mx4N), per-wave C 128x64, BK=64, NT = K/64 K-tiles.
// LDS: dbuf d = tile&1: A[256][64] @ d*32768, B[256][64] @ +16384 (f16 elems).
// OUT: 0 = f16 (+bias, opt relu); 3 = InstanceNorm16+ELU NCHW f32; 4 = f16 +
// bias + residual.
#define STAGE_SLOT(TI, ISB, HALF)                                              \
  {                                                                            \
    f16* dstb_ = smw + ((TI) & 1) * 32768 + ((ISB) ? 16384 : 0) +              \
                 (HALF) * 8192 + ldsw2;                                        \
    const int ld_ = (ISB) ? ldb : lda;                                         \
    const f16* src_ = ((ISB) ? gBs : gAs) + (size_t)((HALF) * 128) * ld_ +     \
                      ((size_t)(TI) << 6);                                     \
    __builtin_amdgcn_global_load_lds(                                          \
        (const __attribute__((address_space(1))) void*)(src_),                 \
        (__attribute__((address_space(3))) void*)(dstb_), 16, 0, 0);           \
    __builtin_amdgcn_global_load_lds(                                          \
        (const __attribute__((address_space(1))) void*)(src_ + (size_t)64 * ld_), \
        (__attribute__((address_space(3))) void*)(dstb_ + 4096), 16, 0, 0);    \
  }

#define VM4 asm volatile("s_waitcnt vmcnt(4)" ::: "memory");
#define VM0 asm volatile("s_waitcnt vmcnt(0)" ::: "memory");
#define VMN

#define PHASE(TI, P, FIRST, DOSTG, STI, SISB, SHALF, VM)                       \
  {                                                                            \
    const f16* Ab_ = smw + ((TI) & 1) * 32768;                                 \
    const f16* Bb_ = Ab_ + 16384;                                              \
    if (FIRST) {                                                               \
      _Pragma("unroll") for (int n = 0; n < 4; ++n) {                          \
        const int r = wn + n * 16 + rm;                                        \
        bf[n][0] = *(const f16x8*)(Bb_ + r * 64 + koff0);                      \
        bf[n][1] = *(const f16x8*)(Bb_ + r * 64 + koff1);                      \
      }                                                                        \
    }                                                                          \
    const int r0_ = wm + (2 * (P)) * 16 + rm;                                  \
    const f16x8 a0k0 = *(const f16x8*)(Ab_ + r0_ * 64 + koff0);                \
    const f16x8 a0k1 = *(const f16x8*)(Ab_ + r0_ * 64 + koff1);                \
    const f16x8 a1k0 = *(const f16x8*)(Ab_ + (r0_ + 16) * 64 + koff0);         \
    const f16x8 a1k1 = *(const f16x8*)(Ab_ + (r0_ + 16) * 64 + koff1);         \
    if (DOSTG) STAGE_SLOT(STI, SISB, SHALF)                                    \
    VM                                                                         \
    __builtin_amdgcn_s_barrier();                                              \
    asm volatile("s_waitcnt lgkmcnt(0)" ::: "memory");                         \
    __builtin_amdgcn_sched_barrier(0);                                         \
    __builtin_amdgcn_s_setprio(1);                                             \
    _Pragma("unroll") for (int n = 0; n < 4; ++n) {                            \
      acc[2 * (P)][n] = __builtin_amdgcn_mfma_f32_16x16x32_f16(                \
          a0k0, bf[n][0], acc[2 * (P)][n], 0, 0, 0);                           \
      acc[2 * (P)][n] = __builtin_amdgcn_mfma_f32_16x16x32_f16(                \
          a0k1, bf[n][1], acc[2 * (P)][n], 0, 0, 0);                           \
      acc[2 * (P) + 1][n] = __builtin_amdgcn_mfma_f32_16x16x32_f16(            \
          a1k0, bf[n][0], acc[2 * (P) + 1][n], 0, 0, 0);                       \
      acc[2 * (P) + 1][n] = __builtin_amdgcn_mfma_f32_16x16x32_f16(            \
          a1k1, bf[n][1], acc[2 * (P) + 1][n], 0, 0, 0);                       \
    }                                                                          \
    __builtin_amdgcn_s_setprio(0);                                             \
    __builtin_amdgcn_s_barrier();                                              \
    __builtin_amdgcn_sched_barrier(0);                                         \
  }

template <int OUT, bool RELU, bool HASB, int NT>
__global__ __launch_bounds__(512) void gemm256_kernel(
    const f16* __restrict__ A, const f16* __restrict__ Bt, void* __restrict__ C,
    const float* __restrict__ bias, const f16* __restrict__ resp,
    int N, int lda, int ldb) {
  __shared__ alignas(16) f16 smem[65536];  // 128 KiB
  f16* smw = smem;
  const int tid = threadIdx.x;
  const int nb = N >> 8;
  const int cpx = gridDim.x >> 3;  // grid always a multiple of 8
  const int wg = (blockIdx.x & 7) * cpx + (blockIdx.x >> 3);
  const int bx = wg % nb, by = wg / nb;
  const int row0 = by << 8, col0 = bx << 8;
  const int lane = tid & 63;
  const int wid = tid >> 6;
  const int wm = (wid >> 2) << 7;  // 0 / 128
  const int wn = (wid & 3) << 6;   // 0 / 64 / 128 / 192
  const int rm = lane & 15;
  const int kg = lane >> 4;
  const int key = rm & 7;
  const int koff0 = ((kg ^ key)) << 3;
  const int koff1 = (((4 + kg) ^ key)) << 3;
  const int schunk = (tid & 7) ^ ((tid >> 3) & 7);
  const f16* gAs = A + (size_t)(row0 + (tid >> 3)) * lda + (schunk << 3);
  const f16* gBs = Bt + (size_t)(col0 + (tid >> 3)) * ldb + (schunk << 3);
  const int ldsw2 = (tid & 0x1C0) << 3;  // wave*512 elems
  f32x4 acc[8][4] = {};
  f16x8 bf[4][2];

  STAGE_SLOT(0, 0, 0)
  STAGE_SLOT(0, 0, 1)
  STAGE_SLOT(0, 1, 0)
  STAGE_SLOT(0, 1, 1)
  STAGE_SLOT(1, 1, 0)
  STAGE_SLOT(1, 1, 1)
  VM4
  __builtin_amdgcn_s_barrier();
  __builtin_amdgcn_sched_barrier(0);

#pragma unroll 1
  for (int j = 0; j < NT / 2 - 1; ++j) {
    const int u = 2 * j, v = u + 1, t2 = u + 2, t3 = u + 3;
    PHASE(u, 0, true,  true, v,  0, 0, VMN)
    PHASE(u, 1, false, true, v,  0, 1, VMN)
    PHASE(u, 2, false, true, t2, 1, 0, VMN)
    PHASE(u, 3, false, true, t2, 1, 1, VM4)
    PHASE(v, 0, true,  true, t2, 0, 0, VMN)
    PHASE(v, 1, false, true, t2, 0, 1, VMN)
    PHASE(v, 2, false, true, t3, 1, 0, VMN)
    PHASE(v, 3, false, true, t3, 1, 1, VM4)
  }
  {  // peeled last iter: only v.A stages remain; vmcnt(0) before reading v.
    const int u = NT - 2, v = NT - 1;
    PHASE(u, 0, true,  true,  v, 0, 0, VMN)
    PHASE(u, 1, false, true,  v, 0, 1, VMN)
    PHASE(u, 2, false, false, 0, 0, 0, VMN)
    PHASE(u, 3, false, false, 0, 0, 0, VM0)
    PHASE(v, 0, true,  false, 0, 0, 0, VMN)
    PHASE(v, 1, false, false, 0, 0, 0, VMN)
    PHASE(v, 2, false, false, 0, 0, 0, VMN)
    PHASE(v, 3, false, false, 0, 0, 0, VMN)
  }

  const int cn = lane & 15;
  const int rg = (lane >> 4) << 2;
  if (OUT == 3) {
    // Fused InstanceNorm2d (no affine) + ELU + NCHW float4 write.
    float* out = (float*)C;
#pragma unroll
    for (int m = 0; m < 8; ++m) {
      const int bidx = (row0 >> 4) + (wm >> 4) + m;
#pragma unroll
      for (int n = 0; n < 4; ++n) {
        const int col = col0 + wn + n * 16 + cn;
        const float v0 = acc[m][n][0], v1 = acc[m][n][1];
        const float v2 = acc[m][n][2], v3 = acc[m][n][3];
        float s = v0 + v1 + v2 + v3;
        s += __shfl_xor(s, 16);
        s += __shfl_xor(s, 32);
        const float mu = s * (1.f / 16.f);
        float q = (v0 - mu) * (v0 - mu) + (v1 - mu) * (v1 - mu) +
                  (v2 - mu) * (v2 - mu) + (v3 - mu) * (v3 - mu);
        q += __shfl_xor(q, 16);
        q += __shfl_xor(q, 32);
        const float rstd = rsqrtf(q * (1.f / 16.f) + 1e-5f);
        float4 z;
        z.x = (v0 - mu) * rstd; z.x = z.x > 0.f ? z.x : expm1f(z.x);
        z.y = (v1 - mu) * rstd; z.y = z.y > 0.f ? z.y : expm1f(z.y);
        z.z = (v2 - mu) * rstd; z.z = z.z > 0.f ? z.z : expm1f(z.z);
        z.w = (v3 - mu) * rstd; z.w = z.w > 0.f ? z.w : expm1f(z.w);
        *(float4*)(out + ((size_t)bidx * 512 + col) * 16 + rg) = z;
      }
    }
  } else {
#pragma unroll
    for (int m = 0; m < 8; ++m) {
#pragma unroll
      for (int n = 0; n < 4; ++n) {
        const int col = col0 + wn + n * 16 + cn;
        const float bv = HASB ? bias[col] : 0.0f;
#pragma unroll
        for (int r = 0; r < 4; ++r) {
          const int row = row0 + wm + m * 16 + rg + r;
          float v = acc[m][n][r] + bv;
          if (OUT == 4) v += (float)resp[(size_t)row * N + col];
          if (RELU) v = v > 0.f ? v : 0.f;
          ((f16*)C)[(size_t)row * N + col] = (f16)v;
        }
      }
    }
  }
}

// ---------------- row LayerNorm over D=512 ----------------------------------
template <bool RES, bool POS>
__global__ void ln_kernel(const f16* in, const f16* res, const float* g,
                          const float* b, const float* pos, f16* out) {
  const int row = (blockIdx.x << 2) + (threadIdx.x >> 6);
  const int lane = threadIdx.x & 63;
  const int c0 = lane << 3;
  float v[8];
  const f16x8 xi = *(const f16x8*)(in + (size_t)row * 512 + c0);
  if (RES) {
    const f16x8 ri = *(const f16x8*)(res + (size_t)row * 512 + c0);
#pragma unroll
    for (int j = 0; j < 8; j++) v[j] = (float)xi[j] + (float)ri[j];
  } else {
#pragma unroll
    for (int j = 0; j < 8; j++) v[j] = (float)xi[j];
  }
  float s = 0;
#pragma unroll
  for (int j = 0; j < 8; j++) s += v[j];
  s = wred_sum(s);
  const float mu = s * (1.f / 512.f);
  float q = 0;
#pragma unroll
  for (int j = 0; j < 8; j++) {
    const float d = v[j] - mu;
    q += d * d;
  }
  q = wred_sum(q);
  const float rstd = rsqrtf(q * (1.f / 512.f) + 1e-5f);
  const int t = row & 15;
  f16x8 o8;
#pragma unroll
  for (int j = 0; j < 8; j++) {
    float o = (v[j] - mu) * rstd * g[c0 + j] + b[c0 + j];
    if (POS) o += pos[t * 512 + c0 + j];
    o8[j] = (f16)o;
  }
  *(f16x8*)(out + (size_t)row * 512 + c0) = o8;
}

// ---------------- lnpack: F[:, :512] = LN(fc_out); F[:, 512:] = X2 ----------
__global__ void lnpack_kernel(const f16* __restrict__ in, const f16* __restrict__ x2,
                              const float* __restrict__ g, const float* __restrict__ b,
                              f16* __restrict__ F) {
  const int row = (blockIdx.x << 2) + (threadIdx.x >> 6);
  const int lane = threadIdx.x & 63;
  const int c0 = lane << 3;
  const f16x8 xi = *(const f16x8*)(in + (size_t)row * 512 + c0);
  float v[8];
#pragma unroll
  for (int j = 0; j < 8; j++) v[j] = (float)xi[j];
  float s = 0;
#pragma unroll
  for (int j = 0; j < 8; j++) s += v[j];
  s = wred_sum(s);
  const float mu = s * (1.f / 512.f);
  float q = 0;
#pragma unroll
  for (int j = 0; j < 8; j++) {
    const float d = v[j] - mu;
    q += d * d;
  }
  q = wred_sum(q);
  const float rstd = rsqrtf(q * (1.f / 512.f) + 1e-5f);
  f16x8 o8;
#pragma unroll
  for (int j = 0; j < 8; j++)
    o8[j] = (f16)((v[j] - mu) * rstd * g[c0 + j] + b[c0 + j]);
  *(f16x8*)(F + (size_t)row * 1024 + c0) = o8;
  const f16x8 x2v = *(const f16x8*)(x2 + (size_t)row * 512 + c0);
  *(f16x8*)(F + (size_t)row * 1024 + 512 + c0) = x2v;
}

// ---------------- attention: MFMA, one (b,head) per wave, 4 waves/block -----
__global__ __launch_bounds__(256) void attn_kernel(const f16* __restrict__ qkv,
                                                   f16* __restrict__ o) {
  __shared__ f16 smem[4][3776];  // per wave: Q[16][72] K[16][72] V[16][72] P[16][20]
  const int wid = threadIdx.x >> 6;
  const int lane = threadIdx.x & 63;
  const int bh = (blockIdx.x << 2) + wid;
  const int b = bh >> 3, h = bh & 7;
  f16* W = smem[wid];
  f16* Qw = W;
  f16* Kw = W + 1152;
  f16* Vw = W + 2304;
  f16* Pw = W + 3456;
  const size_t base = (size_t)b * 24576 + (size_t)h * 64;
#pragma unroll
  for (int i = 0; i < 6; i++) {
    const int c = i * 64 + lane;
    const int t = c / 24;
    const int rem = c - t * 24;
    const int mat = rem >> 3, ch = rem & 7;
    const f16x8 v = *(const f16x8*)(qkv + base + (size_t)t * 1536 + mat * 512 + ch * 8);
    *(f16x8*)(W + mat * 1152 + t * 72 + ch * 8) = v;
  }
  __syncthreads();
  const int rm = lane & 15, kg = lane >> 4;
  f32x4 s4 = {};
  {
    const f16x8 q0 = *(const f16x8*)(Qw + rm * 72 + kg * 8);
    const f16x8 q1 = *(const f16x8*)(Qw + rm * 72 + 32 + kg * 8);
    const f16x8 k0 = *(const f16x8*)(Kw + rm * 72 + kg * 8);
    const f16x8 k1 = *(const f16x8*)(Kw + rm * 72 + 32 + kg * 8);
    s4 = __builtin_amdgcn_mfma_f32_16x16x32_f16(q0, k0, s4, 0, 0, 0);
    s4 = __builtin_amdgcn_mfma_f32_16x16x32_f16(q1, k1, s4, 0, 0, 0);
  }
  float p[4];
#pragma unroll
  for (int r = 0; r < 4; r++) {
    const float sv = s4[r] * 0.125f;
    float m = sv;
    m = fmaxf(m, __shfl_xor(m, 1));
    m = fmaxf(m, __shfl_xor(m, 2));
    m = fmaxf(m, __shfl_xor(m, 4));
    m = fmaxf(m, __shfl_xor(m, 8));
    const float e = expf(sv - m);
    float s = e;
    s += __shfl_xor(s, 1);
    s += __shfl_xor(s, 2);
    s += __shfl_xor(s, 4);
    s += __shfl_xor(s, 8);
    p[r] = e / s;
  }
#pragma unroll
  for (int r = 0; r < 4; r++) Pw[(kg * 4 + r) * 20 + rm] = (f16)p[r];
  __syncthreads();
  const f16x4 pa = *(const f16x4*)(Pw + rm * 20 + kg * 4);
  f32x4 o4[4] = {};
#pragma unroll
  for (int dt = 0; dt < 4; dt++) {
    f16x4 vb;
#pragma unroll
    for (int kk = 0; kk < 4; kk++) vb[kk] = Vw[(kg * 4 + kk) * 72 + dt * 16 + rm];
    o4[dt] = __builtin_amdgcn_mfma_f32_16x16x16f16(pa, vb, o4[dt], 0, 0, 0);
  }
  f16* op = o + (size_t)b * 16 * 512 + (size_t)h * 64;
#pragma unroll
  for (int dt = 0; dt < 4; dt++)
#pragma unroll
    for (int r = 0; r < 4; r++)
      op[(size_t)(kg * 4 + r) * 512 + dt * 16 + rm] = (f16)o4[dt][r];
}

// ---------------- GCN adj-mix + bias + LN + ELU (one block per b) -----------
template <int DG>
__global__ __launch_bounds__(256) void adjmix_kernel(
    const f16* __restrict__ r, const float* __restrict__ adj,
    const float* __restrict__ bias, const float* __restrict__ g,
    const float* __restrict__ bet, f16* __restrict__ out, int ldo) {
  const int b = blockIdx.x;
  const int tid = threadIdx.x;
  __shared__ float agg[16][DG];
  __shared__ float adjs[256];
  if (tid < 256) adjs[tid] = adj[tid];
  __syncthreads();
  const int d0 = tid * 4;
  if (d0 < DG) {
    float acc[16][4];
#pragma unroll
    for (int m = 0; m < 16; m++)
#pragma unroll
      for (int j = 0; j < 4; j++) acc[m][j] = 0.f;
#pragma unroll
    for (int n = 0; n < 16; n++) {
      const f16x4 v = *(const f16x4*)(r + ((size_t)b * 16 + n) * DG + d0);
      const float v0 = (float)v[0], v1 = (float)v[1], v2 = (float)v[2], v3 = (float)v[3];
#pragma unroll
      for (int m = 0; m < 16; m++) {
        const float a = adjs[m * 16 + n];
        acc[m][0] += a * v0;
        acc[m][1] += a * v1;
        acc[m][2] += a * v2;
        acc[m][3] += a * v3;
      }
    }
    const float4 bv = *(const float4*)(bias + d0);
#pragma unroll
    for (int m = 0; m < 16; m++) {
      agg[m][d0 + 0] = acc[m][0] + bv.x;
      agg[m][d0 + 1] = acc[m][1] + bv.y;
      agg[m][d0 + 2] = acc[m][2] + bv.z;
      agg[m][d0 + 3] = acc[m][3] + bv.w;
    }
  }
  __syncthreads();
  const int wave = tid >> 6, lane = tid & 63;
  for (int m = wave; m < 16; m += 4) {
    float s = 0;
#pragma unroll
    for (int j = 0; j < DG / 64; j++) s += agg[m][j * 64 + lane];
    s = wred_sum(s);
    const float mu = s / DG;
    float q = 0;
#pragma unroll
    for (int j = 0; j < DG / 64; j++) {
      const float t = agg[m][j * 64 + lane] - mu;
      q += t * t;
    }
    q = wred_sum(q);
    const float rstd = rsqrtf(q / DG + 1e-5f);
    const size_t grow = (size_t)b * 16 + m;
#pragma unroll
    for (int j = 0; j < DG / 64; j++) {
      const int d = j * 64 + lane;
      float v = (agg[m][d] - mu) * rstd * g[d] + bet[d];
      v = v > 0.f ? v : expm1f(v);
      out[grow * ldo + d] = (f16)v;
    }
  }
}

// ---------------------------------------------------------------------------
extern "C" void kernel_launch(void* const* d_in, const int* in_sizes, int n_in,
                              void* d_out, int out_size, void* d_ws, size_t ws_size,
                              hipStream_t stream) {
  (void)in_sizes; (void)n_in; (void)out_size; (void)ws_size;
  const float* x         = (const float*)d_in[0];
  const float* emb_w     = (const float*)d_in[1];
  const float* emb_b     = (const float*)d_in[2];
  const float* emb_ln_g  = (const float*)d_in[3];
  const float* emb_ln_b  = (const float*)d_in[4];
  const float* pos       = (const float*)d_in[5];
  const float* attn_wq   = (const float*)d_in[6];
  const float* attn_wk   = (const float*)d_in[7];
  const float* attn_wv   = (const float*)d_in[8];
  const float* attn_bq   = (const float*)d_in[9];
  const float* attn_bk   = (const float*)d_in[10];
  const float* attn_bv   = (const float*)d_in[11];
  const float* attn_wo   = (const float*)d_in[12];
  const float* attn_bo   = (const float*)d_in[13];
  const float* ln1_g     = (const float*)d_in[14];
  const float* ln1_b     = (const float*)d_in[15];
  const float* ff_w1     = (const float*)d_in[16];
  const float* ff_b1     = (const float*)d_in[17];
  const float* ff_w2     = (const float*)d_in[18];
  const float* ff_b2     = (const float*)d_in[19];
  const float* ln2_g     = (const float*)d_in[20];
  const float* ln2_b     = (const float*)d_in[21];
  const float* fc_w      = (const float*)d_in[22];
  const float* fc_b      = (const float*)d_in[23];
  const float* fc_ln_g   = (const float*)d_in[24];
  const float* fc_ln_b   = (const float*)d_in[25];
  const float* gcn_w1    = (const float*)d_in[26];
  const float* gcn_b1    = (const float*)d_in[27];
  const float* gcn_ln1_g = (const float*)d_in[28];
  const float* gcn_ln1_b = (const float*)d_in[29];
  const float* gcn_w2    = (const float*)d_in[30];
  const float* gcn_b2    = (const float*)d_in[31];
  const float* gcn_ln2_g = (const float*)d_in[32];
  const float* gcn_ln2_b = (const float*)d_in[33];
  const float* fusion_w  = (const float*)d_in[34];
  const float* fusion_b  = (const float*)d_in[35];
  const float* adj       = (const float*)d_in[36];
  (void)fusion_b;  // cancels under instance norm

  // ---- workspace map (bytes); peak ~212 MiB ----
  char* ws = (char*)d_ws;
  f16*   WF   = (f16*)(ws);                      // 20,971,520 B of weights
  float* BQKV = (float*)(ws + 20971520ull);      //     24,576 B
  f16*   Ap   = (f16*)(ws + 20996096ull);        // 32 MiB  (X0, then X2)
  f16*   Bp   = (f16*)(ws + 54550528ull);        // 32 MiB  (h; B..C = 64 MiB F)
  f16*   Cp   = (f16*)(ws + 88104960ull);        // 32 MiB  (scratch)
  f16*   Qp   = (f16*)(ws + 121659392ull);       // 96 MiB  (qkv / ff scratch)

  // WF layout (f16 element offsets)
  const size_t o_emb = 0, o_qkv = 262144, o_wo = 3407872, o_ff1 = 4456448,
               o_ff2 = 6553600, o_fc = 8650752, o_g1 = 8912896, o_g2 = 9437184,
               o_fus = 9961472;

  WTable tab{};
  int ntab = 0, tbase = 0;
  auto add = [&](const float* s, f16* dst, int K, int N, int mode) {
    WDesc& w = tab.d[ntab++];
    w.src = s; w.dst = dst; w.K = K; w.N = N;
    w.tiles_n = N / 32; w.tile_base = tbase; w.mode = mode;
    tbase += (K / 32) * (N / 32);
  };
  add(emb_w, WF + o_emb, 512, 512, 0);
  for (int l = 0; l < 4; l++) {
    add(attn_wq + l * 262144, WF + o_qkv + (size_t)l * 786432, 512, 512, 0);
    add(attn_wk + l * 262144, WF + o_qkv + (size_t)l * 786432 + 262144, 512, 512, 0);
    add(attn_wv + l * 262144, WF + o_qkv + (size_t)l * 786432 + 524288, 512, 512, 0);
  }
  for (int l = 0; l < 4; l++)
    add(attn_wo + l * 262144, WF + o_wo + (size_t)l * 262144, 512, 512, 0);
  for (int l = 0; l < 4; l++)
    add(ff_w1 + l * 524288, WF + o_ff1 + (size_t)l * 524288, 512, 1024, 0);
  for (int l = 0; l < 4; l++)
    add(ff_w2 + l * 524288, WF + o_ff2 + (size_t)l * 524288, 1024, 512, 0);
  add(fc_w, WF + o_fc, 512, 512, 0);
  add(gcn_w1, WF + o_g1, 512, 1024, 0);
  add(gcn_w2, WF + o_g2, 1024, 512, 0);
  add(fusion_w, WF + o_fus, 512, 1024, 1);  // already [N,K]: straight copy
  tab.n = ntab;

  wconvert_kernel<<<tbase, 256, 0, stream>>>(tab);
  biaspack_kernel<<<24, 256, 0, stream>>>(attn_bq, attn_bk, attn_bv, BQKV);
  prep_kernel<<<2048, 256, 0, stream>>>(x, Ap);  // X0 in A

  // ---- GCN branch ----
  gemm256_kernel<0, false, false, 8><<<512, 512, 0, stream>>>(
      Ap, WF + o_g1, Qp, nullptr, nullptr, 1024, 512, 512);
  adjmix_kernel<1024><<<2048, 256, 0, stream>>>(
      Qp, adj, gcn_b1, gcn_ln1_g, gcn_ln1_b, Bp, 1024);
  gemm256_kernel<0, false, false, 16><<<256, 512, 0, stream>>>(
      Bp, WF + o_g2, Qp, nullptr, nullptr, 512, 1024, 1024);

  // ---- transformer embed (frees A for X2) ----
  gemm256_kernel<0, false, true, 8><<<256, 512, 0, stream>>>(
      Ap, WF + o_emb, Cp, emb_b, nullptr, 512, 512, 512);
  ln_kernel<false, true><<<8192, 256, 0, stream>>>(
      Cp, nullptr, emb_ln_g, emb_ln_b, pos, Bp);  // h in B

  // GCN adjmix2 -> X2 in A (A free now)
  adjmix_kernel<512><<<2048, 256, 0, stream>>>(
      Qp, adj, gcn_b2, gcn_ln2_g, gcn_ln2_b, Ap, 512);

  // ---- transformer layers (h=B, scratch=C, Q free) ----
  for (int i = 0; i < 4; i++) {
    gemm256_kernel<0, false, true, 8><<<768, 512, 0, stream>>>(
        Bp, WF + o_qkv + (size_t)i * 786432, Qp, BQKV + i * 1536, nullptr,
        1536, 512, 512);
    attn_kernel<<<4096, 256, 0, stream>>>(Qp, Cp);
    // WO GEMM with fused residual (+h) -> Qp
    gemm256_kernel<4, false, true, 8><<<256, 512, 0, stream>>>(
        Cp, WF + o_wo + (size_t)i * 262144, Qp, attn_bo + i * 512, Bp,
        512, 512, 512);
    ln_kernel<false, false><<<8192, 256, 0, stream>>>(
        Qp, nullptr, ln1_g + i * 512, ln1_b + i * 512, nullptr, Bp);
    gemm256_kernel<0, true, true, 8><<<512, 512, 0, stream>>>(
        Bp, WF + o_ff1 + (size_t)i * 524288, Qp, ff_b1 + i * 1024, nullptr,
        1024, 512, 512);
    // FF2 GEMM with fused residual (+h) -> Qp+33M
    gemm256_kernel<4, false, true, 16><<<256, 512, 0, stream>>>(
        Qp, WF + o_ff2 + (size_t)i * 524288, Qp + 33554432ull, ff_b2 + i * 512,
        Bp, 512, 1024, 1024);
    ln_kernel<false, false><<<8192, 256, 0, stream>>>(
        Qp + 33554432ull, nullptr, ln2_g + i * 512, ln2_b + i * 512, nullptr, Bp);
  }

  // ---- fc -> Qp; lnpack: F[:, :512]=LN(Qp), F[:, 512:]=X2 (F = Bp..Cp) ----
  gemm256_kernel<0, false, true, 8><<<256, 512, 0, stream>>>(
      Bp, WF + o_fc, Qp, fc_b, nullptr, 512, 512, 512);
  lnpack_kernel<<<8192, 256, 0, stream>>>(Qp, Ap, fc_ln_g, fc_ln_b, Bp);

  // ---- fusion GEMM K=1024 with fused InstanceNorm+ELU+NCHW epilogue ----
  gemm256_kernel<3, false, false, 16><<<256, 512, 0, stream>>>(
      Bp, WF + o_fus, d_out, nullptr, nullptr, 512, 1024, 1024);
}